// Round 7
// baseline (4537.364 us; speedup 1.0000x reference)
//
#include <hip/hip_runtime.h>
#include <stdint.h>
#include <math.h>

typedef short short8 __attribute__((ext_vector_type(8)));
typedef float floatx4 __attribute__((ext_vector_type(4)));
typedef uint32_t uint4v __attribute__((ext_vector_type(4)));

#define MFMA(a, b, c) __builtin_amdgcn_mfma_f32_16x16x32_bf16((a), (b), (c), 0, 0, 0)

#define B_   64
#define S_   256
#define DIN  512
#define DH   1024
#define G3   3072
#define DOUT 64
#define M_   (B_ * S_)  // 16384
#define NBLK 64         // dataflow blocks: 64 col-chunks of 16 cols

// bf16 negative-NaN pair. |h| < 1 always (tanh/sigmoid bounded) and f2bf of a
// finite float can never produce 0xFFC0 -> impossible as real data.
#define POISON 0xFFC0FFC0u

#define AGENT_LD_U64(p) __hip_atomic_load((p), __ATOMIC_RELAXED, __HIP_MEMORY_SCOPE_AGENT)
#define AGENT_ST_U32(p, v) __hip_atomic_store((p), (v), __ATOMIC_RELAXED, __HIP_MEMORY_SCOPE_AGENT)

__device__ __forceinline__ unsigned short f2bf(float f) {
    union { float f; uint32_t u; } v; v.f = f;
    uint32_t u = v.u;
    uint32_t r = (u + 0x7fffu + ((u >> 16) & 1u)) >> 16;  // RNE
    return (unsigned short)r;
}
__device__ __forceinline__ float bf2f(unsigned short s) {
    union { uint32_t u; float f; } v; v.u = ((uint32_t)s) << 16; return v.f;
}
__device__ __forceinline__ short8 ld8(const unsigned short* p) {
    return *reinterpret_cast<const short8*>(p);
}
__device__ __forceinline__ float fast_sigmoid(float x) {
    return 1.f / (1.f + __expf(-x));
}
__device__ __forceinline__ float fast_tanh(float x) {
    return 1.f - 2.f / (__expf(2.f * x) + 1.f);
}

// ---------------- elementwise: fp32 -> bf16 cast ----------------
__global__ void cast_bf16_kernel(const float* __restrict__ src,
                                 unsigned short* __restrict__ dst, int n) {
    int i = blockIdx.x * 256 + threadIdx.x;
    if (i < n) dst[i] = f2bf(src[i]);
}

// ---------------- poison the hs buffer (ws is 0xAA-poisoned, not poison-coded) ----
__global__ void poison_hs_kernel(uint4v* hs4) {
    size_t i = (size_t)blockIdx.x * 256 + threadIdx.x;
    size_t n = (size_t)M_ * DH / 8;
    uint4v pv = {POISON, POISON, POISON, POISON};
    if (i < n) hs4[i] = pv;
}

// ---------------- embedding gather into [s*64+b][512] bf16 ----------------
__global__ void gather_kernel(const int* __restrict__ x, const float* __restrict__ emb,
                              unsigned short* __restrict__ xe) {
    int g = blockIdx.x * 256 + threadIdx.x;  // 16384*512 total
    int m = g >> 9;          // row = s*64+b
    int k = g & 511;
    int s = m >> 6, b = m & 63;
    int tok = x[b * S_ + s];
    xe[(size_t)m * DIN + k] = f2bf(emb[(size_t)tok * DIN + k]);
}

// ---------------- bt-GEMM: C[M,N] bf16 = A[M,K] @ W[N,K]^T + bias ----------------
__global__ __launch_bounds__(256) void gemm_bt_bias(
        const unsigned short* __restrict__ A, const unsigned short* __restrict__ W,
        const float* __restrict__ bias, unsigned short* __restrict__ C,
        int M, int N, int K) {
    __shared__ __align__(16) unsigned short As[128 * 32];
    __shared__ __align__(16) unsigned short Ws[128 * 32];
    int tid = threadIdx.x;
    int lane = tid & 63, wv = tid >> 6;
    int wm = wv >> 1, wn = wv & 1;
    int q = lane >> 4, l15 = lane & 15;
    int bm = blockIdx.x, bn = blockIdx.y;

    floatx4 acc[4][4];
    floatx4 z = {0.f, 0.f, 0.f, 0.f};
    for (int i = 0; i < 4; i++) for (int j = 0; j < 4; j++) acc[i][j] = z;

    int row_s = tid >> 1;
    int col_s = (tid & 1) * 16;
    const unsigned short* Ab = A + (size_t)(bm * 128 + row_s) * K + col_s;
    const unsigned short* Wb = W + (size_t)(bn * 128 + row_s) * K + col_s;
    unsigned short* AsW = &As[row_s * 32 + col_s];
    unsigned short* WsW = &Ws[row_s * 32 + col_s];

    for (int k0 = 0; k0 < K; k0 += 32) {
        __syncthreads();
        *reinterpret_cast<short8*>(AsW)     = ld8(Ab + k0);
        *reinterpret_cast<short8*>(AsW + 8) = ld8(Ab + k0 + 8);
        *reinterpret_cast<short8*>(WsW)     = ld8(Wb + k0);
        *reinterpret_cast<short8*>(WsW + 8) = ld8(Wb + k0 + 8);
        __syncthreads();
        short8 af[4], wf[4];
        for (int t = 0; t < 4; t++) {
            af[t] = ld8(&As[(wm * 64 + t * 16 + l15) * 32 + q * 8]);
            wf[t] = ld8(&Ws[(wn * 64 + t * 16 + l15) * 32 + q * 8]);
        }
        for (int i = 0; i < 4; i++)
            for (int j = 0; j < 4; j++)
                acc[i][j] = MFMA(af[i], wf[j], acc[i][j]);
    }
    for (int i = 0; i < 4; i++) {
        int row = bm * 128 + wm * 64 + i * 16 + q * 4;
        for (int j = 0; j < 4; j++) {
            int col = bn * 128 + wn * 64 + j * 16 + l15;
            float bv = bias[col];
            for (int r = 0; r < 4; r++)
                C[(size_t)(row + r) * N + col] = f2bf(acc[i][j][r] + bv);
        }
    }
}

// ---------------- GRU recurrence: pure wave-granular dataflow ----------------
// 64 blocks x 256 thr (4 waves). Block owns 16 h-cols; its W_hh slice (16 cols
// x 3 gates x K=1024 = 98 KB) lives in LDS (XOR-swizzled), loaded ONCE.
// Wave m (0..3) owns batch rows m*16..m*16+15 x the block's 16 cols x FULL K.
// Consequences:
//   * no K-split -> no LDS reduction -> no gate-wave specialization
//   * ZERO per-step barriers (only one __syncthreads ever, for the W stage)
//   * each wave self-times on DATA: sentinel-poll its 16-row h(s-1) panel
//     (hs pre-poisoned with impossible bf16 NaN pairs; producers just issue
//     relaxed agent stores, fire-and-forget), 96 chained MFMAs, gates for its
//     own 16x16 patch in-register, store, next step.
// Dependency graph: 4 independent 64-wave all-to-alls (rows partition by m).
// A fast wave slips into step s+1 immediately -- jitter is absorbed by
// pipeline skew instead of being summed by barriers 256 times.
// HARDENING vs the unmeasured R4 attempt: s_sleep backoff after a failed poll
// (none on the success path) so 256 spinning waves cannot storm the L2/MALL
// read path and starve the producers' posted writes. (s_sleep takes a literal
// constant -> branch to two constant-arg calls; R5's ternary arg was the
// compile failure.)
// Liveness: no barriers, no circular waits (step s polls only step s-1 data,
// produced unconditionally); agent stores are MALL-visible and agent atomic
// loads observe them (round-0/1-proven machinery) -> termination guaranteed.
__global__ __launch_bounds__(256, 1) void gru_dataflow(
        const unsigned short* __restrict__ gi,   // [256][64][3072] bf16 (incl b_ih)
        const unsigned short* __restrict__ whh,  // [3072][1024] bf16
        const float* __restrict__ b_hh,          // [3072]
        unsigned short* __restrict__ hs) {       // [256][64][1024] bf16, pre-poisoned
    const int tid = threadIdx.x;
    const int lane = tid & 63, m = tid >> 6;     // m: row tile 0..3
    const int q = lane >> 4, l15 = lane & 15;
    const int jc = blockIdx.x;                   // col chunk 0..63
    const int j = jc * 16 + l15;                 // this lane's h-col

    __shared__ __align__(16) unsigned short wl[48 * 1024];  // 98304 B

    // ---- one-time weight stage into LDS, 16B-slot XOR swizzle ----
    // row = g*16 + c (c = col-in-chunk), 128 slots of 16B per row.
    // physical slot = logical slot ^ (row & 7)  (T2-style, breaks the
    // all-rows-same-bank pattern of the 2048B row stride).
    for (int i = tid; i < 48 * 128; i += 256) {
        int row = i >> 7, slot = i & 127;
        int G = (row >> 4) * 1024 + jc * 16 + (row & 15);
        short8 v = ld8(whh + (size_t)G * 1024 + slot * 8);
        *reinterpret_cast<short8*>(&wl[row * 1024 + ((slot ^ (row & 7)) * 8)]) = v;
    }
    __syncthreads();  // the only barrier in this kernel

    // B-frag read pointers. Lane (l15, q) needs logical slot kk*4+q of row
    // g*16+l15; physical slot = (kk*4+q) ^ (l15&7). Decompose:
    //   slot' = (kk>>1)*8 + ((kk&1)^cb)*4 + q4, cb = (l15>>2)&1, q4 = q^(l15&3)
    // -> two base pointers per gate (kk even/odd), imm offset (kk>>1)*128B.
    const int c  = l15 & 7;
    const int q4 = q ^ (c & 3);
    const int cb = (c >> 2) & 1;
    const unsigned short* wp[3][2];
#pragma unroll
    for (int g = 0; g < 3; g++) {
        const unsigned short* rb = &wl[(g * 16 + l15) * 1024];
        wp[g][0] = rb + (cb * 4 + q4) * 8;         // kk even
        wp[g][1] = rb + (((1 ^ cb) * 4 + q4)) * 8; // kk odd
    }

    const float bhr = b_hh[j], bhz = b_hh[1024 + j], bhn = b_hh[2048 + j];
    float hreg[4] = {0.f, 0.f, 0.f, 0.f};
    float gir[4], giz[4], gin[4];
#pragma unroll
    for (int r = 0; r < 4; r++) {
        int b = m * 16 + q * 4 + r;               // initial gi prefetch (s=0)
        gir[r] = bf2f(gi[(size_t)b * G3 + j]);
        giz[r] = bf2f(gi[(size_t)b * G3 + 1024 + j]);
        gin[r] = bf2f(gi[(size_t)b * G3 + 2048 + j]);
    }

    union Frag { short8 v[32]; unsigned long long d[64]; uint32_t w[128]; };
    floatx4 zf = {0.f, 0.f, 0.f, 0.f};

    for (int s = 0; s < S_; s++) {
        floatx4 acc[3] = {zf, zf, zf};
        if (s > 0) {
            // ---- sentinel-poll the full A panel: rows m*16..+15, all K ----
            // lane l15 = row, q = k-subgroup; chunk kk covers k = kk*32+q*8..+7
            const unsigned long long* hp = (const unsigned long long*)
                (hs + ((size_t)(s - 1) * B_ + m * 16 + l15) * DH + q * 8);
            Frag f;
            int tries = 0;
            for (;;) {
#pragma unroll
                for (int kk = 0; kk < 32; kk++) {
                    f.d[kk * 2]     = AGENT_LD_U64(hp + kk * 8);
                    f.d[kk * 2 + 1] = AGENT_LD_U64(hp + kk * 8 + 1);
                }
                uint32_t ok = 1u;
#pragma unroll
                for (int t = 0; t < 128; t++) ok &= (uint32_t)(f.w[t] != POISON);
                if (__all(ok != 0u)) break;
                // backoff: keep the success path hot, throttle the retry storm
                ++tries;
                if (tries < 8) {
                    __builtin_amdgcn_s_sleep(2);
                } else {
                    __builtin_amdgcn_s_sleep(8);
                }
            }
            // ---- 96 MFMAs: 3 gate chains x 32 k-steps, full K in-wave ----
#pragma unroll
            for (int kk = 0; kk < 32; kk++) {
                const int p = kk & 1, o = (kk >> 1) * 64;
                acc[0] = MFMA(f.v[kk], *(const short8*)(wp[0][p] + o), acc[0]);
                acc[1] = MFMA(f.v[kk], *(const short8*)(wp[1][p] + o), acc[1]);
                acc[2] = MFMA(f.v[kk], *(const short8*)(wp[2][p] + o), acc[2]);
            }
        }

        // ---- gates for this wave's own 16x16 patch (C-frag: col=l15, row=q*4+r) ----
        uint32_t* ho32 = (uint32_t*)(hs + (size_t)s * B_ * DH);
#pragma unroll
        for (int r = 0; r < 4; r++) {
            int b = m * 16 + q * 4 + r;
            float rg = fast_sigmoid(gir[r] + acc[0][r] + bhr);
            float zg = fast_sigmoid(giz[r] + acc[1][r] + bhz);
            float ng = fast_tanh(gin[r] + rg * (acc[2][r] + bhn));
            float h = (1.f - zg) * ng + zg * hreg[r];
            hreg[r] = h;
            // pack bf16 pair across adjacent lanes (cols j, j+1); even lane stores u32
            float hnb = __shfl_xor(h, 1);
            if ((l15 & 1) == 0) {
                uint32_t pk = (uint32_t)f2bf(h) | ((uint32_t)f2bf(hnb) << 16);
                AGENT_ST_U32(&ho32[((size_t)b * DH + j) >> 1], pk);
            }
        }
        // fire-and-forget stores; consumers detect the data itself.
        if (s + 1 < S_) {
            const unsigned short* gp = gi + (size_t)(s + 1) * B_ * G3;
#pragma unroll
            for (int r = 0; r < 4; r++) {
                int b = m * 16 + q * 4 + r;
                gir[r] = bf2f(gp[(size_t)b * G3 + j]);
                giz[r] = bf2f(gp[(size_t)b * G3 + 1024 + j]);
                gin[r] = bf2f(gp[(size_t)b * G3 + 2048 + j]);
            }
        }
    }
}

// ---------------- FC + log_softmax, fused ----------------
__global__ __launch_bounds__(256) void fc_logsoftmax(
        const unsigned short* __restrict__ hs,    // [16384][1024] bf16, row = s*64+b
        const unsigned short* __restrict__ fcw,   // [64][1024] bf16
        const float* __restrict__ fcb,            // [64]
        float* __restrict__ out) {                // [B][S][64]
    int tid = threadIdx.x;
    int lane = tid & 63, mt = tid >> 6;
    int q = lane >> 4, l15 = lane & 15;
    int r0 = blockIdx.x * 64;

    floatx4 acc[4];
    floatx4 z = {0.f, 0.f, 0.f, 0.f};
    for (int nt = 0; nt < 4; nt++) acc[nt] = z;

    const unsigned short* Ap = hs + (size_t)(r0 + mt * 16 + l15) * DH + q * 8;
    const unsigned short* Wp = fcw + (size_t)l15 * DH + q * 8;
    for (int k0 = 0; k0 < DH; k0 += 32) {
        short8 a = ld8(Ap + k0);
        for (int nt = 0; nt < 4; nt++)
            acc[nt] = MFMA(a, ld8(Wp + (size_t)nt * 16 * DH + k0), acc[nt]);
    }

    float bv[4];
    for (int nt = 0; nt < 4; nt++) bv[nt] = fcb[nt * 16 + l15];

    for (int r = 0; r < 4; r++) {
        float v[4];
        for (int nt = 0; nt < 4; nt++) v[nt] = acc[nt][r] + bv[nt];
        float m = fmaxf(fmaxf(v[0], v[1]), fmaxf(v[2], v[3]));
        for (int off = 1; off < 16; off <<= 1) m = fmaxf(m, __shfl_xor(m, off));
        float se = __expf(v[0] - m) + __expf(v[1] - m) + __expf(v[2] - m) + __expf(v[3] - m);
        for (int off = 1; off < 16; off <<= 1) se += __shfl_xor(se, off);
        float L = logf(se);
        int row = r0 + mt * 16 + q * 4 + r;  // = s*64 + b
        int srow = row >> 6, brow = row & 63;
        float* op = out + (size_t)(brow * S_ + srow) * DOUT;
        for (int nt = 0; nt < 4; nt++) op[nt * 16 + l15] = v[nt] - m - L;
    }
}

extern "C" void kernel_launch(void* const* d_in, const int* in_sizes, int n_in,
                              void* d_out, int out_size, void* d_ws, size_t ws_size,
                              hipStream_t stream) {
    const int*   x    = (const int*)d_in[0];
    const float* emb  = (const float*)d_in[1];
    const float* w_ih = (const float*)d_in[2];
    const float* w_hh = (const float*)d_in[3];
    const float* b_ih = (const float*)d_in[4];
    const float* b_hh = (const float*)d_in[5];
    const float* fc_w = (const float*)d_in[6];
    const float* fc_b = (const float*)d_in[7];
    float* out = (float*)d_out;

    char* p = (char*)d_ws;
    unsigned short* xe    = (unsigned short*)p; p += (size_t)M_ * DIN * 2;   // 16 MB
    unsigned short* gi    = (unsigned short*)p; p += (size_t)M_ * G3 * 2;    // 100.7 MB
    unsigned short* wih_b = (unsigned short*)p; p += (size_t)G3 * DIN * 2;   // 3 MB
    unsigned short* whh_b = (unsigned short*)p; p += (size_t)G3 * DH * 2;    // 6.3 MB
    unsigned short* fcw_b = (unsigned short*)p; p += (size_t)DOUT * DH * 2;  // 128 KB
    unsigned short* hs    = (unsigned short*)p; p += (size_t)M_ * DH * 2;    // 33.6 MB

    poison_hs_kernel<<<(M_ * DH / 8 + 255) / 256, 256, 0, stream>>>((uint4v*)hs);
    cast_bf16_kernel<<<(G3 * DIN + 255) / 256, 256, 0, stream>>>(w_ih, wih_b, G3 * DIN);
    cast_bf16_kernel<<<(G3 * DH + 255) / 256, 256, 0, stream>>>(w_hh, whh_b, G3 * DH);
    cast_bf16_kernel<<<(DOUT * DH + 255) / 256, 256, 0, stream>>>(fc_w, fcw_b, DOUT * DH);
    gather_kernel<<<(M_ * DIN) / 256, 256, 0, stream>>>(x, emb, xe);

    gemm_bt_bias<<<dim3(M_ / 128, G3 / 128), 256, 0, stream>>>(
        xe, wih_b, b_ih, gi, M_, G3, DIN);

    gru_dataflow<<<NBLK, 256, 0, stream>>>(gi, whh_b, b_hh, hs);

    fc_logsoftmax<<<M_ / 64, 256, 0, stream>>>(hs, fcw_b, fc_b, out);
}

// Round 8
// 3261.508 us; speedup vs baseline: 1.3912x; 1.3912x over previous
//
#include <hip/hip_runtime.h>
#include <stdint.h>
#include <math.h>

typedef short short8 __attribute__((ext_vector_type(8)));
typedef float floatx4 __attribute__((ext_vector_type(4)));
typedef uint32_t uint4v __attribute__((ext_vector_type(4)));

#define MFMA(a, b, c) __builtin_amdgcn_mfma_f32_16x16x32_bf16((a), (b), (c), 0, 0, 0)

#define B_   64
#define S_   256
#define DIN  512
#define DH   1024
#define G3   3072
#define DOUT 64
#define M_   (B_ * S_)  // 16384
#define NBLK 256        // 8 groups (XCDs) x 32 blocks; 1 block/CU

// bf16 negative-NaN pair. |h| < 1 always (tanh/sigmoid bounded) and f2bf of a
// finite float can never produce 0xFFC0 -> impossible as real data.
#define POISON 0xFFC0FFC0u

#define AGENT_ST_U32(p, v) __hip_atomic_store((p), (v), __ATOMIC_RELAXED, __HIP_MEMORY_SCOPE_AGENT)

__device__ __forceinline__ unsigned short f2bf(float f) {
    union { float f; uint32_t u; } v; v.f = f;
    uint32_t u = v.u;
    uint32_t r = (u + 0x7fffu + ((u >> 16) & 1u)) >> 16;  // RNE
    return (unsigned short)r;
}
__device__ __forceinline__ float bf2f(unsigned short s) {
    union { uint32_t u; float f; } v; v.u = ((uint32_t)s) << 16; return v.f;
}
__device__ __forceinline__ short8 ld8(const unsigned short* p) {
    return *reinterpret_cast<const short8*>(p);
}
__device__ __forceinline__ float fast_sigmoid(float x) {
    return 1.f / (1.f + __expf(-x));
}
__device__ __forceinline__ float fast_tanh(float x) {
    return 1.f - 2.f / (__expf(2.f * x) + 1.f);
}

// 128B fragment load, L1-bypass / L2-SERVED (sc0): within one XCD the shared
// L2 is the handoff point -- producers' PLAIN writeback stores land there in
// ~100-200cy and update the very lines these polls read. L2-hit RT ~300cy.
__device__ __forceinline__ void poll8_l2(const unsigned short* p,
        short8& a0, short8& a1, short8& a2, short8& a3,
        short8& a4, short8& a5, short8& a6, short8& a7) {
    asm volatile(
        "global_load_dwordx4 %0, %8, off sc0\n\t"
        "global_load_dwordx4 %1, %8, off offset:64 sc0\n\t"
        "global_load_dwordx4 %2, %8, off offset:128 sc0\n\t"
        "global_load_dwordx4 %3, %8, off offset:192 sc0\n\t"
        "global_load_dwordx4 %4, %8, off offset:256 sc0\n\t"
        "global_load_dwordx4 %5, %8, off offset:320 sc0\n\t"
        "global_load_dwordx4 %6, %8, off offset:384 sc0\n\t"
        "global_load_dwordx4 %7, %8, off offset:448 sc0\n\t"
        "s_waitcnt vmcnt(0)"
        : "=&v"(a0), "=&v"(a1), "=&v"(a2), "=&v"(a3),
          "=&v"(a4), "=&v"(a5), "=&v"(a6), "=&v"(a7)
        : "v"(p)
        : "memory");
}
// Fallback variant: full bypass to MALL (sc0 sc1). Used every 8th retry so the
// protocol stays correct even if block->XCD placement is not round-robin
// (producers' AGENT mirror stores are always MALL-visible). Never hangs.
__device__ __forceinline__ void poll8_mall(const unsigned short* p,
        short8& a0, short8& a1, short8& a2, short8& a3,
        short8& a4, short8& a5, short8& a6, short8& a7) {
    asm volatile(
        "global_load_dwordx4 %0, %8, off sc0 sc1\n\t"
        "global_load_dwordx4 %1, %8, off offset:64 sc0 sc1\n\t"
        "global_load_dwordx4 %2, %8, off offset:128 sc0 sc1\n\t"
        "global_load_dwordx4 %3, %8, off offset:192 sc0 sc1\n\t"
        "global_load_dwordx4 %4, %8, off offset:256 sc0 sc1\n\t"
        "global_load_dwordx4 %5, %8, off offset:320 sc0 sc1\n\t"
        "global_load_dwordx4 %6, %8, off offset:384 sc0 sc1\n\t"
        "global_load_dwordx4 %7, %8, off offset:448 sc0 sc1\n\t"
        "s_waitcnt vmcnt(0)"
        : "=&v"(a0), "=&v"(a1), "=&v"(a2), "=&v"(a3),
          "=&v"(a4), "=&v"(a5), "=&v"(a6), "=&v"(a7)
        : "v"(p)
        : "memory");
}

// ---------------- elementwise: fp32 -> bf16 cast ----------------
__global__ void cast_bf16_kernel(const float* __restrict__ src,
                                 unsigned short* __restrict__ dst, int n) {
    int i = blockIdx.x * 256 + threadIdx.x;
    if (i < n) dst[i] = f2bf(src[i]);
}

// ---------------- poison the hs buffer (ws is 0xAA-poisoned, not poison-coded) ----
__global__ void poison_hs_kernel(uint4v* hs4) {
    size_t i = (size_t)blockIdx.x * 256 + threadIdx.x;
    size_t n = (size_t)M_ * DH / 8;
    uint4v pv = {POISON, POISON, POISON, POISON};
    if (i < n) hs4[i] = pv;
}

// ---------------- embedding gather into [s*64+b][512] bf16 ----------------
__global__ void gather_kernel(const int* __restrict__ x, const float* __restrict__ emb,
                              unsigned short* __restrict__ xe) {
    int g = blockIdx.x * 256 + threadIdx.x;  // 16384*512 total
    int m = g >> 9;          // row = s*64+b
    int k = g & 511;
    int s = m >> 6, b = m & 63;
    int tok = x[b * S_ + s];
    xe[(size_t)m * DIN + k] = f2bf(emb[(size_t)tok * DIN + k]);
}

// ---------------- bt-GEMM: C[M,N] bf16 = A[M,K] @ W[N,K]^T + bias ----------------
__global__ __launch_bounds__(256) void gemm_bt_bias(
        const unsigned short* __restrict__ A, const unsigned short* __restrict__ W,
        const float* __restrict__ bias, unsigned short* __restrict__ C,
        int M, int N, int K) {
    __shared__ __align__(16) unsigned short As[128 * 32];
    __shared__ __align__(16) unsigned short Ws[128 * 32];
    int tid = threadIdx.x;
    int lane = tid & 63, wv = tid >> 6;
    int wm = wv >> 1, wn = wv & 1;
    int q = lane >> 4, l15 = lane & 15;
    int bm = blockIdx.x, bn = blockIdx.y;

    floatx4 acc[4][4];
    floatx4 z = {0.f, 0.f, 0.f, 0.f};
    for (int i = 0; i < 4; i++) for (int j = 0; j < 4; j++) acc[i][j] = z;

    int row_s = tid >> 1;
    int col_s = (tid & 1) * 16;
    const unsigned short* Ab = A + (size_t)(bm * 128 + row_s) * K + col_s;
    const unsigned short* Wb = W + (size_t)(bn * 128 + row_s) * K + col_s;
    unsigned short* AsW = &As[row_s * 32 + col_s];
    unsigned short* WsW = &Ws[row_s * 32 + col_s];

    for (int k0 = 0; k0 < K; k0 += 32) {
        __syncthreads();
        *reinterpret_cast<short8*>(AsW)     = ld8(Ab + k0);
        *reinterpret_cast<short8*>(AsW + 8) = ld8(Ab + k0 + 8);
        *reinterpret_cast<short8*>(WsW)     = ld8(Wb + k0);
        *reinterpret_cast<short8*>(WsW + 8) = ld8(Wb + k0 + 8);
        __syncthreads();
        short8 af[4], wf[4];
        for (int t = 0; t < 4; t++) {
            af[t] = ld8(&As[(wm * 64 + t * 16 + l15) * 32 + q * 8]);
            wf[t] = ld8(&Ws[(wn * 64 + t * 16 + l15) * 32 + q * 8]);
        }
        for (int i = 0; i < 4; i++)
            for (int j = 0; j < 4; j++)
                acc[i][j] = MFMA(af[i], wf[j], acc[i][j]);
    }
    for (int i = 0; i < 4; i++) {
        int row = bm * 128 + wm * 64 + i * 16 + q * 4;
        for (int j = 0; j < 4; j++) {
            int col = bn * 128 + wn * 64 + j * 16 + l15;
            float bv = bias[col];
            for (int r = 0; r < 4; r++)
                C[(size_t)(row + r) * N + col] = f2bf(acc[i][j][r] + bv);
        }
    }
}

// ---------------- persistent GRU recurrence: XCD-LOCAL batch split, L2 handoff ----
// The B=64 batch rows are independent chains. Group x = blockIdx.x & 7 (HW
// round-robins blocks across the 8 XCDs -- confirmed by R3's FETCH collapse
// 272->117MB -- so a group's 32 blocks share ONE L2) owns rows x*8..x*8+7 and
// computes ALL 1024 h-cols for them each step. Full W_hh register-resident per
// group. The per-step all-to-all is CONFINED to the group's 32 same-L2 blocks.
//
// FIX vs R3 (which had locality but no speedup): producers store h TWICE --
//   (1) PLAIN volatile store: write-through L1 into the LOCAL L2 (~150cy),
//       updating the very line consumers poll;
//   (2) AGENT mirror store to the same address: write-through to MALL, keeping
//       the cross-XCD fallback and inter-kernel visibility sound.
// Consumers sentinel-poll with sc0 (L1-bypass, L2-SERVED) loads: the poll now
// hits FRESH data in L2 (~300cy RT) instead of stale lines / MALL round-trips.
// Same value to same address -> any writeback ordering is benign.
//
// No flags, no vmcnt drains on the chain, ONE s_barrier per step (red[]
// double-buffered: reader(s) < barrier(s+1) <= writer(s+2)).
// Liveness: fallback poll every 8th retry goes sc0|sc1 (MALL) where the agent
// mirror is always visible -> worst case slow, never a hang.
__global__ __launch_bounds__(512, 2) void gru_persistent(
        const unsigned short* __restrict__ gi,   // [256][64][3072] bf16 (incl b_ih)
        const unsigned short* __restrict__ whh,  // [3072][1024] bf16
        const float* __restrict__ b_hh,          // [3072]
        unsigned short* __restrict__ hs) {       // [256][64][1024] bf16, pre-poisoned
    const int tid = threadIdx.x;
    const int lane = tid & 63, wv = tid >> 6;
    const int nc = wv & 1, kh = wv >> 1;         // kh: K quarter 0..3, nc: col half
    const int q = lane >> 4, l15 = lane & 15;
    const int x  = blockIdx.x & 7;               // group (expected XCD)
    const int jc = blockIdx.x >> 3;              // col chunk 0..31 (32 cols each)
    const int j  = jc * 32 + nc * 16 + l15;      // this wave's h-col 0..1023
    const int arow = x * 8 + (l15 & 7);          // A row (8 real rows duplicated)

    __shared__ float red[2][3][2][3][64][4];     // [s&1][kh-1][nc][g][lane][r] = 36 KB

    // ---- register-resident weights: rows {j, 1024+j, 2048+j}, K quarter kh ----
    short8 wfrag[3][8];
#pragma unroll
    for (int g = 0; g < 3; g++)
#pragma unroll
        for (int kk = 0; kk < 8; kk++)
            wfrag[g][kk] = ld8(whh + (size_t)(g * 1024 + j) * DH + kh * 256 + kk * 32 + q * 8);

    float bhr = 0.f, bhz = 0.f, bhn = 0.f;
    float hreg[4] = {0.f, 0.f, 0.f, 0.f};
    float gir[4], giz[4], gin[4];
    if (kh == 0) {
        bhr = b_hh[j]; bhz = b_hh[1024 + j]; bhn = b_hh[2048 + j];
        if (q < 2) {
#pragma unroll
            for (int r = 0; r < 4; r++) {
                int b = x * 8 + q * 4 + r;       // initial gi prefetch (s=0)
                gir[r] = bf2f(gi[(size_t)b * G3 + j]);
                giz[r] = bf2f(gi[(size_t)b * G3 + 1024 + j]);
                gin[r] = bf2f(gi[(size_t)b * G3 + 2048 + j]);
            }
        }
    }

    union Frag { short8 v[8]; uint32_t w[32]; };

    for (int s = 0; s < S_; s++) {
        const int pb = s & 1;
        // ---- MFMA phase: gh partials for this K quarter (poll = load) ----
        floatx4 zf = {0.f, 0.f, 0.f, 0.f};
        floatx4 acc[3] = {zf, zf, zf};
        if (s > 0) {
            const unsigned short* hp =
                hs + ((size_t)(s - 1) * B_ + arow) * DH + kh * 256 + q * 8;
            Frag f;
            int tries = 0;
            for (;;) {
                if ((tries & 7) == 7)
                    poll8_mall(hp, f.v[0], f.v[1], f.v[2], f.v[3],
                                   f.v[4], f.v[5], f.v[6], f.v[7]);
                else
                    poll8_l2(hp, f.v[0], f.v[1], f.v[2], f.v[3],
                                 f.v[4], f.v[5], f.v[6], f.v[7]);
                uint32_t ok = 1u;
#pragma unroll
                for (int t = 0; t < 32; t++) ok &= (uint32_t)(f.w[t] != POISON);
                if (__all(ok != 0u)) break;
                ++tries;
                if (tries >= 16) {
                    __builtin_amdgcn_s_sleep(4);   // throttle only when clearly stuck
                }
            }
#pragma unroll
            for (int kk = 0; kk < 8; kk++)
#pragma unroll
                for (int g = 0; g < 3; g++)
                    acc[g] = MFMA(f.v[kk], wfrag[g][kk], acc[g]);
        }

        // ---- cross-wave K reduction (vector LDS writes) ----
        if (kh > 0) {
#pragma unroll
            for (int g = 0; g < 3; g++)
                *reinterpret_cast<floatx4*>(&red[pb][kh - 1][nc][g][lane][0]) = acc[g];
        }
        asm volatile("s_waitcnt lgkmcnt(0)" ::: "memory");
        __builtin_amdgcn_s_barrier();
        asm volatile("" ::: "memory");

        if (kh == 0) {
            // ---- gate phase (waves 0,1; one per col half) ----
#pragma unroll
            for (int p = 0; p < 3; p++)
#pragma unroll
                for (int g = 0; g < 3; g++) {
                    floatx4 v = *reinterpret_cast<const floatx4*>(&red[pb][p][nc][g][lane][0]);
                    acc[g] += v;
                }
            if (q < 2) {                          // rows 0..7 are real
                uint32_t* ho32 = (uint32_t*)(hs + (size_t)s * B_ * DH);
#pragma unroll
                for (int r = 0; r < 4; r++) {
                    int b = x * 8 + q * 4 + r;
                    float rg = fast_sigmoid(gir[r] + acc[0][r] + bhr);
                    float zg = fast_sigmoid(giz[r] + acc[1][r] + bhz);
                    float ng = fast_tanh(gin[r] + rg * (acc[2][r] + bhn));
                    float h = (1.f - zg) * ng + zg * hreg[r];
                    hreg[r] = h;
                    // pack bf16 pair across adjacent lanes (cols j, j+1)
                    float hnb = __shfl_xor(h, 1);
                    if ((l15 & 1) == 0) {
                        uint32_t pk = (uint32_t)f2bf(h) | ((uint32_t)f2bf(hnb) << 16);
                        uint32_t* dst = &ho32[((size_t)b * DH + j) >> 1];
                        *(volatile uint32_t*)dst = pk;  // (1) local L2, fast handoff
                        AGENT_ST_U32(dst, pk);          // (2) MALL mirror, fallback+next kernel
                    }
                }
                if (s + 1 < S_) {
                    // gi prefetch for s+1 (HBM latency hides under next poll)
                    const unsigned short* gp = gi + (size_t)(s + 1) * B_ * G3;
#pragma unroll
                    for (int r = 0; r < 4; r++) {
                        int b = x * 8 + q * 4 + r;
                        gir[r] = bf2f(gp[(size_t)b * G3 + j]);
                        giz[r] = bf2f(gp[(size_t)b * G3 + 1024 + j]);
                        gin[r] = bf2f(gp[(size_t)b * G3 + 2048 + j]);
                    }
                }
            }
        }
    }
}

// ---------------- FC + log_softmax, fused ----------------
__global__ __launch_bounds__(256) void fc_logsoftmax(
        const unsigned short* __restrict__ hs,    // [16384][1024] bf16, row = s*64+b
        const unsigned short* __restrict__ fcw,   // [64][1024] bf16
        const float* __restrict__ fcb,            // [64]
        float* __restrict__ out) {                // [B][S][64]
    int tid = threadIdx.x;
    int lane = tid & 63, mt = tid >> 6;
    int q = lane >> 4, l15 = lane & 15;
    int r0 = blockIdx.x * 64;

    floatx4 acc[4];
    floatx4 z = {0.f, 0.f, 0.f, 0.f};
    for (int nt = 0; nt < 4; nt++) acc[nt] = z;

    const unsigned short* Ap = hs + (size_t)(r0 + mt * 16 + l15) * DH + q * 8;
    const unsigned short* Wp = fcw + (size_t)l15 * DH + q * 8;
    for (int k0 = 0; k0 < DH; k0 += 32) {
        short8 a = ld8(Ap + k0);
        for (int nt = 0; nt < 4; nt++)
            acc[nt] = MFMA(a, ld8(Wp + (size_t)nt * 16 * DH + k0), acc[nt]);
    }

    float bv[4];
    for (int nt = 0; nt < 4; nt++) bv[nt] = fcb[nt * 16 + l15];

    for (int r = 0; r < 4; r++) {
        float v[4];
        for (int nt = 0; nt < 4; nt++) v[nt] = acc[nt][r] + bv[nt];
        float m = fmaxf(fmaxf(v[0], v[1]), fmaxf(v[2], v[3]));
        for (int off = 1; off < 16; off <<= 1) m = fmaxf(m, __shfl_xor(m, off));
        float se = __expf(v[0] - m) + __expf(v[1] - m) + __expf(v[2] - m) + __expf(v[3] - m);
        for (int off = 1; off < 16; off <<= 1) se += __shfl_xor(se, off);
        float L = logf(se);
        int row = r0 + mt * 16 + q * 4 + r;  // = s*64 + b
        int srow = row >> 6, brow = row & 63;
        float* op = out + (size_t)(brow * S_ + srow) * DOUT;
        for (int nt = 0; nt < 4; nt++) op[nt * 16 + l15] = v[nt] - m - L;
    }
}

extern "C" void kernel_launch(void* const* d_in, const int* in_sizes, int n_in,
                              void* d_out, int out_size, void* d_ws, size_t ws_size,
                              hipStream_t stream) {
    const int*   x    = (const int*)d_in[0];
    const float* emb  = (const float*)d_in[1];
    const float* w_ih = (const float*)d_in[2];
    const float* w_hh = (const float*)d_in[3];
    const float* b_ih = (const float*)d_in[4];
    const float* b_hh = (const float*)d_in[5];
    const float* fc_w = (const float*)d_in[6];
    const float* fc_b = (const float*)d_in[7];
    float* out = (float*)d_out;

    char* p = (char*)d_ws;
    unsigned short* xe    = (unsigned short*)p; p += (size_t)M_ * DIN * 2;   // 16 MB
    unsigned short* gi    = (unsigned short*)p; p += (size_t)M_ * G3 * 2;    // 100.7 MB
    unsigned short* wih_b = (unsigned short*)p; p += (size_t)G3 * DIN * 2;   // 3 MB
    unsigned short* whh_b = (unsigned short*)p; p += (size_t)G3 * DH * 2;    // 6.3 MB
    unsigned short* fcw_b = (unsigned short*)p; p += (size_t)DOUT * DH * 2;  // 128 KB
    unsigned short* hs    = (unsigned short*)p; p += (size_t)M_ * DH * 2;    // 33.6 MB

    poison_hs_kernel<<<(M_ * DH / 8 + 255) / 256, 256, 0, stream>>>((uint4v*)hs);
    cast_bf16_kernel<<<(G3 * DIN + 255) / 256, 256, 0, stream>>>(w_ih, wih_b, G3 * DIN);
    cast_bf16_kernel<<<(G3 * DH + 255) / 256, 256, 0, stream>>>(w_hh, whh_b, G3 * DH);
    cast_bf16_kernel<<<(DOUT * DH + 255) / 256, 256, 0, stream>>>(fc_w, fcw_b, DOUT * DH);
    gather_kernel<<<(M_ * DIN) / 256, 256, 0, stream>>>(x, emb, xe);

    gemm_bt_bias<<<dim3(M_ / 128, G3 / 128), 256, 0, stream>>>(
        xe, wih_b, b_ih, gi, M_, G3, DIN);

    gru_persistent<<<NBLK, 512, 0, stream>>>(gi, whh_b, b_hh, hs);

    fc_logsoftmax<<<M_ / 64, 256, 0, stream>>>(hs, fcw_b, fc_b, out);
}

// Round 9
// 1631.996 us; speedup vs baseline: 2.7803x; 1.9985x over previous
//
#include <hip/hip_runtime.h>
#include <stdint.h>
#include <math.h>

typedef short short8 __attribute__((ext_vector_type(8)));
typedef float floatx4 __attribute__((ext_vector_type(4)));

#define MFMA(a, b, c) __builtin_amdgcn_mfma_f32_16x16x32_bf16((a), (b), (c), 0, 0, 0)

#define B_   64
#define S_   256
#define DIN  512
#define DH   1024
#define G3   3072
#define DOUT 64
#define M_   (B_ * S_)  // 16384
#define NBLK 128        // persistent blocks: 64 col-chunks x 2 batch halves
#define NFLAG (S_ * 2 * 128)  // [s][mh][jc*2+mt] ready flags

#define AGENT_LD_U32(p) __hip_atomic_load((p), __ATOMIC_RELAXED, __HIP_MEMORY_SCOPE_AGENT)
#define AGENT_ST_U32(p, v) __hip_atomic_store((p), (v), __ATOMIC_RELAXED, __HIP_MEMORY_SCOPE_AGENT)

__device__ __forceinline__ unsigned short f2bf(float f) {
    union { float f; uint32_t u; } v; v.f = f;
    uint32_t u = v.u;
    uint32_t r = (u + 0x7fffu + ((u >> 16) & 1u)) >> 16;  // RNE
    return (unsigned short)r;
}
__device__ __forceinline__ float bf2f(unsigned short s) {
    union { uint32_t u; float f; } v; v.u = ((uint32_t)s) << 16; return v.f;
}
__device__ __forceinline__ short8 ld8(const unsigned short* p) {
    return *reinterpret_cast<const short8*>(p);
}
__device__ __forceinline__ float fast_sigmoid(float x) {
    return 1.f / (1.f + __expf(-x));
}
__device__ __forceinline__ float fast_tanh(float x) {
    return 1.f - 2.f / (__expf(2.f * x) + 1.f);
}

// ---------------- elementwise: fp32 -> bf16 cast ----------------
__global__ void cast_bf16_kernel(const float* __restrict__ src,
                                 unsigned short* __restrict__ dst, int n) {
    int i = blockIdx.x * 256 + threadIdx.x;
    if (i < n) dst[i] = f2bf(src[i]);
}

// ---------------- zero the flag region (ws is poisoned 0xAA!) ----------------
__global__ void init_flags_kernel(unsigned int* flags) {
    int i = blockIdx.x * 256 + threadIdx.x;
    if (i < NFLAG) flags[i] = 0u;
}

// ---------------- embedding gather into [s*64+b][512] bf16 ----------------
__global__ void gather_kernel(const int* __restrict__ x, const float* __restrict__ emb,
                              unsigned short* __restrict__ xe) {
    int g = blockIdx.x * 256 + threadIdx.x;  // 16384*512 total
    int m = g >> 9;          // row = s*64+b
    int k = g & 511;
    int s = m >> 6, b = m & 63;
    int tok = x[b * S_ + s];
    xe[(size_t)m * DIN + k] = f2bf(emb[(size_t)tok * DIN + k]);
}

// ---------------- bt-GEMM: C[M,N] bf16 = A[M,K] @ W[N,K]^T + bias ----------------
__global__ __launch_bounds__(256) void gemm_bt_bias(
        const unsigned short* __restrict__ A, const unsigned short* __restrict__ W,
        const float* __restrict__ bias, unsigned short* __restrict__ C,
        int M, int N, int K) {
    __shared__ __align__(16) unsigned short As[128 * 32];
    __shared__ __align__(16) unsigned short Ws[128 * 32];
    int tid = threadIdx.x;
    int lane = tid & 63, wv = tid >> 6;
    int wm = wv >> 1, wn = wv & 1;
    int q = lane >> 4, l15 = lane & 15;
    int bm = blockIdx.x, bn = blockIdx.y;

    floatx4 acc[4][4];
    floatx4 z = {0.f, 0.f, 0.f, 0.f};
    for (int i = 0; i < 4; i++) for (int j = 0; j < 4; j++) acc[i][j] = z;

    int row_s = tid >> 1;
    int col_s = (tid & 1) * 16;
    const unsigned short* Ab = A + (size_t)(bm * 128 + row_s) * K + col_s;
    const unsigned short* Wb = W + (size_t)(bn * 128 + row_s) * K + col_s;
    unsigned short* AsW = &As[row_s * 32 + col_s];
    unsigned short* WsW = &Ws[row_s * 32 + col_s];

    for (int k0 = 0; k0 < K; k0 += 32) {
        __syncthreads();
        *reinterpret_cast<short8*>(AsW)     = ld8(Ab + k0);
        *reinterpret_cast<short8*>(AsW + 8) = ld8(Ab + k0 + 8);
        *reinterpret_cast<short8*>(WsW)     = ld8(Wb + k0);
        *reinterpret_cast<short8*>(WsW + 8) = ld8(Wb + k0 + 8);
        __syncthreads();
        short8 af[4], wf[4];
        for (int t = 0; t < 4; t++) {
            af[t] = ld8(&As[(wm * 64 + t * 16 + l15) * 32 + q * 8]);
            wf[t] = ld8(&Ws[(wn * 64 + t * 16 + l15) * 32 + q * 8]);
        }
        for (int i = 0; i < 4; i++)
            for (int j = 0; j < 4; j++)
                acc[i][j] = MFMA(af[i], wf[j], acc[i][j]);
    }
    for (int i = 0; i < 4; i++) {
        int row = bm * 128 + wm * 64 + i * 16 + q * 4;
        for (int j = 0; j < 4; j++) {
            int col = bn * 128 + wn * 64 + j * 16 + l15;
            float bv = bias[col];
            for (int r = 0; r < 4; r++)
                C[(size_t)(row + r) * N + col] = f2bf(acc[i][j][r] + bv);
        }
    }
}

// ---------------- persistent GRU recurrence ----------------
// Round-1-proven skeleton (1548us): 128 blocks x 512 thr, flags, single poller
// wave, raw barriers, vmcnt(0) drain before publish, gi prefetch after.
//
// ONE change this round -- the hs LAYOUT. The old hs[b][1024] put each 128B
// line's 64 cols across 4 jc-chunks -> every line was co-written by 4 blocks
// on 4 DIFFERENT XCDs every step (consecutive blockIdx round-robin XCDs).
// Cross-XCD partial-line write-through merging at the MALL is the one
// mechanism every prior protocol variant shared (and the only invariant never
// varied). New layout: hs[s][mh][jc][mt][16 rows][16 cols] -- a 512B tile
// (4 lines) written ENTIRELY by one wave in 4 store instructions. No line is
// ever co-written by two blocks. Consumer reads become 1KB/instr fully
// coalesced (8 full lines) vs half-line utilization before. Byte counts
// identical; pure access-pattern change.
__global__ __launch_bounds__(512, 2) void gru_persistent(
        const unsigned short* __restrict__ gi,   // [256][64][3072] bf16 (incl b_ih)
        const unsigned short* __restrict__ whh,  // [3072][1024] bf16
        const float* __restrict__ b_hh,          // [3072]
        unsigned short* __restrict__ hs,         // tiled: [256][2][64][2][16][16] bf16
        unsigned int* flags) {                   // [256][2][128]: [s][mh][jc*2+mt]
    const int tid = threadIdx.x;
    const int lane = tid & 63, wv = tid >> 6;
    const int mt = wv & 1, kh = wv >> 1;         // kh 0..3
    const int q = lane >> 4, l15 = lane & 15;
    const int jc = blockIdx.x >> 1, mh = blockIdx.x & 1;
    const int j = jc * 16 + l15;                 // h-col 0..1023
    const int brow0 = mh * 32 + mt * 16;         // wave's 16 batch rows

    __shared__ float red[2][3][2][3][64][4];     // [s&1][kh-1][mt][g][lane][r] = 36 KB

    // ---- register-resident weight fragments: rows {j, 1024+j, 2048+j}, K quarter kh ----
    short8 wfrag[3][8];
#pragma unroll
    for (int g = 0; g < 3; g++)
#pragma unroll
        for (int kk = 0; kk < 8; kk++)
            wfrag[g][kk] = ld8(whh + (size_t)(g * 1024 + j) * DH + kh * 256 + kk * 32 + q * 8);

    float bhr = 0.f, bhz = 0.f, bhn = 0.f;
    float hreg[4];
    float gir[4], giz[4], gin[4];
    if (kh == 0) {
        bhr = b_hh[j]; bhz = b_hh[1024 + j]; bhn = b_hh[2048 + j];
#pragma unroll
        for (int r = 0; r < 4; r++) {
            hreg[r] = 0.f;
            int b = brow0 + q * 4 + r;           // initial gi prefetch (s=0)
            gir[r] = bf2f(gi[(size_t)b * G3 + j]);
            giz[r] = bf2f(gi[(size_t)b * G3 + 1024 + j]);
            gin[r] = bf2f(gi[(size_t)b * G3 + 2048 + j]);
        }
    }

    for (int s = 0; s < S_; s++) {
        const int pb = s & 1;
        // ---- MFMA phase: gh partials for this K quarter ----
        floatx4 zf = {0.f, 0.f, 0.f, 0.f};
        floatx4 acc[3] = {zf, zf, zf};
        if (s > 0) {
            // tiled read: A rows = mh*32 + mt*16 + l15 (tile row l15, producer
            // tile mt of half mh); k = kh*256 + kk*32 + q*8 -> source tile
            // jc_k = kh*16 + kk*2 + (q>>1), 16B half (q&1). Each ld8
            // instruction covers 2 full tiles (8 cache lines), perfectly
            // coalesced, 1KB/instr.
            const unsigned short* hb =
                hs + ((size_t)((s - 1) * 2 + mh) * 64) * 512 + mt * 256
                   + l15 * 16 + (q & 1) * 8;
            const int jbase = (kh * 16 + (q >> 1)) * 512;
#pragma unroll
            for (int kk = 0; kk < 8; kk++) {
                short8 a = ld8(hb + jbase + kk * 1024);  // kk*2 tiles = 1024 ushort
#pragma unroll
                for (int g = 0; g < 3; g++)
                    acc[g] = MFMA(a, wfrag[g][kk], acc[g]);
            }
        }

        // ---- cross-wave K reduction (vector LDS writes) ----
        if (kh > 0) {
#pragma unroll
            for (int g = 0; g < 3; g++)
                *reinterpret_cast<floatx4*>(&red[pb][kh - 1][mt][g][lane][0]) = acc[g];
        }
        // red handoff: LDS writes visible, then raw barrier (no vmcnt drain -
        // outstanding gi prefetch / flag stores stay in flight).
        asm volatile("s_waitcnt lgkmcnt(0)" ::: "memory");
        __builtin_amdgcn_s_barrier();
        asm volatile("" ::: "memory");

        if (kh == 0) {
            // ---- gate phase (the two kh==0 waves) ----
#pragma unroll
            for (int p = 0; p < 3; p++)
#pragma unroll
                for (int g = 0; g < 3; g++) {
                    floatx4 v = *reinterpret_cast<const floatx4*>(&red[pb][p][mt][g][lane][0]);
                    acc[g] += v;
                }
            // this wave's OWN 512B tile: [s][mh][jc][mt][16][16]
            uint32_t* ht = (uint32_t*)(hs +
                ((size_t)(s * 2 + mh) * 64 + jc) * 512 + mt * 256);
#pragma unroll
            for (int r = 0; r < 4; r++) {
                float rg = fast_sigmoid(gir[r] + acc[0][r] + bhr);
                float zg = fast_sigmoid(giz[r] + acc[1][r] + bhz);
                float ng = fast_tanh(gin[r] + rg * (acc[2][r] + bhn));
                float h = (1.f - zg) * ng + zg * hreg[r];
                hreg[r] = h;
                // pack bf16 pair across adjacent lanes (tile cols l15, l15+1)
                float hnb = __shfl_xor(h, 1);
                if ((l15 & 1) == 0) {
                    uint32_t pk = (uint32_t)f2bf(h) | ((uint32_t)f2bf(hnb) << 16);
                    // tile row = q*4+r (stride 8 dwords), col pair l15>>1.
                    // 4 store instrs (r=0..3) fully cover the 4-line tile:
                    // single-writer lines, no cross-XCD merge.
                    AGENT_ST_U32(&ht[(q * 4 + r) * 8 + (l15 >> 1)], pk);
                }
            }
            if (s + 1 < S_) {
                // own-wave drain: stores at coherence point once vmcnt==0.
                // Then publish this wave's flag.
                asm volatile("" ::: "memory");
                asm volatile("s_waitcnt vmcnt(0)" ::: "memory");
                if (lane == 0)
                    AGENT_ST_U32(&flags[((s << 1) + mh) * 128 + jc * 2 + mt], 1u);
                // gi prefetch for s+1 AFTER publish: HBM latency off the chain
                const unsigned short* gp = gi + (size_t)(s + 1) * B_ * G3;
#pragma unroll
                for (int r = 0; r < 4; r++) {
                    int b = brow0 + q * 4 + r;
                    gir[r] = bf2f(gp[(size_t)b * G3 + j]);
                    giz[r] = bf2f(gp[(size_t)b * G3 + 1024 + j]);
                    gin[r] = bf2f(gp[(size_t)b * G3 + 2048 + j]);
                }
            }
        } else if (wv == 7) {
            // ---- dedicated poller wave: wait for all 128 producer flags of
            // step s (my mh half). 64 lanes x 2 dwords = 2 cache lines.
            if (s + 1 < S_) {
                const unsigned int* fp = flags + ((s << 1) + mh) * 128 + lane;
                for (;;) {
                    unsigned int f0 = AGENT_LD_U32(fp);
                    unsigned int f1 = AGENT_LD_U32(fp + 64);
                    if (__all((f0 != 0u) && (f1 != 0u))) break;
                    __builtin_amdgcn_s_sleep(1);
                }
                asm volatile("" ::: "memory");
            }
        }
        // waves 2..6 fall straight through and PARK here (no spin traffic).
        asm volatile("" ::: "memory");
        __builtin_amdgcn_s_barrier();
        asm volatile("" ::: "memory");
    }
}

// ---------------- FC + log_softmax, fused (tiled hs reader) ----------------
__global__ __launch_bounds__(256) void fc_logsoftmax(
        const unsigned short* __restrict__ hs,    // tiled: [256][2][64][2][16][16]
        const unsigned short* __restrict__ fcw,   // [64][1024] bf16
        const float* __restrict__ fcb,            // [64]
        float* __restrict__ out) {                // [B][S][64]
    int tid = threadIdx.x;
    int lane = tid & 63, mt = tid >> 6;
    int q = lane >> 4, l15 = lane & 15;
    int s = blockIdx.x;                          // rows s*64 .. s*64+63

    floatx4 acc[4];
    floatx4 z = {0.f, 0.f, 0.f, 0.f};
    for (int nt = 0; nt < 4; nt++) acc[nt] = z;

    // A row b = mt*16 + l15 -> half mh=b>>5, producer tile mtb=(b>>4)&1, row b&15
    int b = mt * 16 + l15;
    int mh = b >> 5, mtb = (b >> 4) & 1, r16 = b & 15;
    const unsigned short* Ab =
        hs + ((size_t)(s * 2 + mh) * 64) * 512 + mtb * 256
           + r16 * 16 + (q & 1) * 8;
    const int jq = (q >> 1) * 512;               // jc half-step from q
    const unsigned short* Wp = fcw + (size_t)l15 * DH + q * 8;
    for (int k0 = 0; k0 < DH; k0 += 32) {
        // k = k0 + q*8 (+0..7): source tile jc = (k0>>4) + (q>>1)
        short8 a = ld8(Ab + (k0 >> 4) * 512 + jq);
        for (int nt = 0; nt < 4; nt++)
            acc[nt] = MFMA(a, ld8(Wp + (size_t)nt * 16 * DH + k0), acc[nt]);
    }

    float bv[4];
    for (int nt = 0; nt < 4; nt++) bv[nt] = fcb[nt * 16 + l15];

    for (int r = 0; r < 4; r++) {
        float v[4];
        for (int nt = 0; nt < 4; nt++) v[nt] = acc[nt][r] + bv[nt];
        float m = fmaxf(fmaxf(v[0], v[1]), fmaxf(v[2], v[3]));
        for (int off = 1; off < 16; off <<= 1) m = fmaxf(m, __shfl_xor(m, off));
        float se = __expf(v[0] - m) + __expf(v[1] - m) + __expf(v[2] - m) + __expf(v[3] - m);
        for (int off = 1; off < 16; off <<= 1) se += __shfl_xor(se, off);
        float L = logf(se);
        int brow = mt * 16 + q * 4 + r;          // C-frag row = batch index
        float* op = out + (size_t)(brow * S_ + s) * DOUT;
        for (int nt = 0; nt < 4; nt++) op[nt * 16 + l15] = v[nt] - m - L;
    }
}

extern "C" void kernel_launch(void* const* d_in, const int* in_sizes, int n_in,
                              void* d_out, int out_size, void* d_ws, size_t ws_size,
                              hipStream_t stream) {
    const int*   x    = (const int*)d_in[0];
    const float* emb  = (const float*)d_in[1];
    const float* w_ih = (const float*)d_in[2];
    const float* w_hh = (const float*)d_in[3];
    const float* b_ih = (const float*)d_in[4];
    const float* b_hh = (const float*)d_in[5];
    const float* fc_w = (const float*)d_in[6];
    const float* fc_b = (const float*)d_in[7];
    float* out = (float*)d_out;

    char* p = (char*)d_ws;
    unsigned int*   flags = (unsigned int*)p;   p += NFLAG * 4;              // 256 KB
    unsigned short* xe    = (unsigned short*)p; p += (size_t)M_ * DIN * 2;   // 16 MB
    unsigned short* gi    = (unsigned short*)p; p += (size_t)M_ * G3 * 2;    // 100.7 MB
    unsigned short* wih_b = (unsigned short*)p; p += (size_t)G3 * DIN * 2;   // 3 MB
    unsigned short* whh_b = (unsigned short*)p; p += (size_t)G3 * DH * 2;    // 6.3 MB
    unsigned short* fcw_b = (unsigned short*)p; p += (size_t)DOUT * DH * 2;  // 128 KB
    unsigned short* hs    = (unsigned short*)p; p += (size_t)M_ * DH * 2;    // 33.6 MB

    init_flags_kernel<<<(NFLAG + 255) / 256, 256, 0, stream>>>(flags);
    cast_bf16_kernel<<<(G3 * DIN + 255) / 256, 256, 0, stream>>>(w_ih, wih_b, G3 * DIN);
    cast_bf16_kernel<<<(G3 * DH + 255) / 256, 256, 0, stream>>>(w_hh, whh_b, G3 * DH);
    cast_bf16_kernel<<<(DOUT * DH + 255) / 256, 256, 0, stream>>>(fc_w, fcw_b, DOUT * DH);
    gather_kernel<<<(M_ * DIN) / 256, 256, 0, stream>>>(x, emb, xe);

    gemm_bt_bias<<<dim3(M_ / 128, G3 / 128), 256, 0, stream>>>(
        xe, wih_b, b_ih, gi, M_, G3, DIN);

    gru_persistent<<<NBLK, 512, 0, stream>>>(gi, whh_b, b_hh, hs, flags);

    fc_logsoftmax<<<S_, 256, 0, stream>>>(hs, fcw_b, fc_b, out);
}

// Round 10
// 1171.810 us; speedup vs baseline: 3.8721x; 1.3927x over previous
//
#include <hip/hip_runtime.h>
#include <stdint.h>
#include <math.h>

typedef short short8 __attribute__((ext_vector_type(8)));
typedef float floatx4 __attribute__((ext_vector_type(4)));

#define MFMA(a, b, c) __builtin_amdgcn_mfma_f32_16x16x32_bf16((a), (b), (c), 0, 0, 0)

#define B_   64
#define S_   256
#define DIN  512
#define DH   1024
#define G3   3072
#define DOUT 64
#define M_   (B_ * S_)  // 16384
#define NBLK 128        // persistent blocks: 64 col-chunks x 2 batch halves
#define FPAD 16         // dwords per flag slot (64B): 128B line = 2 slots = ONE block
#define NFLAG (S_ * 2 * 128 * FPAD)  // padded [s][mh][jc*2+mt] ready flags (4MB)

#define AGENT_LD_U32(p) __hip_atomic_load((p), __ATOMIC_RELAXED, __HIP_MEMORY_SCOPE_AGENT)
#define AGENT_ST_U32(p, v) __hip_atomic_store((p), (v), __ATOMIC_RELAXED, __HIP_MEMORY_SCOPE_AGENT)

__device__ __forceinline__ unsigned short f2bf(float f) {
    union { float f; uint32_t u; } v; v.f = f;
    uint32_t u = v.u;
    uint32_t r = (u + 0x7fffu + ((u >> 16) & 1u)) >> 16;  // RNE
    return (unsigned short)r;
}
__device__ __forceinline__ float bf2f(unsigned short s) {
    union { uint32_t u; float f; } v; v.u = ((uint32_t)s) << 16; return v.f;
}
__device__ __forceinline__ short8 ld8(const unsigned short* p) {
    return *reinterpret_cast<const short8*>(p);
}
__device__ __forceinline__ float fast_sigmoid(float x) {
    return 1.f / (1.f + __expf(-x));
}
__device__ __forceinline__ float fast_tanh(float x) {
    return 1.f - 2.f / (__expf(2.f * x) + 1.f);
}

// ---------------- elementwise: fp32 -> bf16 cast ----------------
__global__ void cast_bf16_kernel(const float* __restrict__ src,
                                 unsigned short* __restrict__ dst, int n) {
    int i = blockIdx.x * 256 + threadIdx.x;
    if (i < n) dst[i] = f2bf(src[i]);
}

// ---------------- zero the flag region (ws is poisoned 0xAA!) ----------------
__global__ void init_flags_kernel(unsigned int* flags) {
    int i = blockIdx.x * 256 + threadIdx.x;
    if (i < NFLAG) flags[i] = 0u;
}

// ---------------- embedding gather into [s*64+b][512] bf16 ----------------
__global__ void gather_kernel(const int* __restrict__ x, const float* __restrict__ emb,
                              unsigned short* __restrict__ xe) {
    int g = blockIdx.x * 256 + threadIdx.x;  // 16384*512 total
    int m = g >> 9;          // row = s*64+b
    int k = g & 511;
    int s = m >> 6, b = m & 63;
    int tok = x[b * S_ + s];
    xe[(size_t)m * DIN + k] = f2bf(emb[(size_t)tok * DIN + k]);
}

// ---------------- bt-GEMM: C[M,N] bf16 = A[M,K] @ W[N,K]^T + bias ----------------
__global__ __launch_bounds__(256) void gemm_bt_bias(
        const unsigned short* __restrict__ A, const unsigned short* __restrict__ W,
        const float* __restrict__ bias, unsigned short* __restrict__ C,
        int M, int N, int K) {
    __shared__ __align__(16) unsigned short As[128 * 32];
    __shared__ __align__(16) unsigned short Ws[128 * 32];
    int tid = threadIdx.x;
    int lane = tid & 63, wv = tid >> 6;
    int wm = wv >> 1, wn = wv & 1;
    int q = lane >> 4, l15 = lane & 15;
    int bm = blockIdx.x, bn = blockIdx.y;

    floatx4 acc[4][4];
    floatx4 z = {0.f, 0.f, 0.f, 0.f};
    for (int i = 0; i < 4; i++) for (int j = 0; j < 4; j++) acc[i][j] = z;

    int row_s = tid >> 1;
    int col_s = (tid & 1) * 16;
    const unsigned short* Ab = A + (size_t)(bm * 128 + row_s) * K + col_s;
    const unsigned short* Wb = W + (size_t)(bn * 128 + row_s) * K + col_s;
    unsigned short* AsW = &As[row_s * 32 + col_s];
    unsigned short* WsW = &Ws[row_s * 32 + col_s];

    for (int k0 = 0; k0 < K; k0 += 32) {
        __syncthreads();
        *reinterpret_cast<short8*>(AsW)     = ld8(Ab + k0);
        *reinterpret_cast<short8*>(AsW + 8) = ld8(Ab + k0 + 8);
        *reinterpret_cast<short8*>(WsW)     = ld8(Wb + k0);
        *reinterpret_cast<short8*>(WsW + 8) = ld8(Wb + k0 + 8);
        __syncthreads();
        short8 af[4], wf[4];
        for (int t = 0; t < 4; t++) {
            af[t] = ld8(&As[(wm * 64 + t * 16 + l15) * 32 + q * 8]);
            wf[t] = ld8(&Ws[(wn * 64 + t * 16 + l15) * 32 + q * 8]);
        }
        for (int i = 0; i < 4; i++)
            for (int j = 0; j < 4; j++)
                acc[i][j] = MFMA(af[i], wf[j], acc[i][j]);
    }
    for (int i = 0; i < 4; i++) {
        int row = bm * 128 + wm * 64 + i * 16 + q * 4;
        for (int j = 0; j < 4; j++) {
            int col = bn * 128 + wn * 64 + j * 16 + l15;
            float bv = bias[col];
            for (int r = 0; r < 4; r++)
                C[(size_t)(row + r) * N + col] = f2bf(acc[i][j][r] + bv);
        }
    }
}

// ---------------- persistent GRU recurrence ----------------
// R9 skeleton (1390us): tiled single-writer hs (validated: removed cross-XCD
// partial-line h merges, -150us), flags, single poller wave, raw barriers,
// vmcnt(0) drain before publish, gi prefetch after.
//
// ONE change this round: the FLAG array had the exact same pathology R9 fixed
// for h -- 128 flag dwords = 2 cache lines, each co-written by 64 blocks on
// all 8 XCDs every step, while the poller hammers the same lines. 64
// serialized cross-XCD write-through merges per line per step, directly on the
// publish->observe chain. Fix: pad each flag to a 64B slot; slot pairing puts
// the two waves (mt=0,1) of ONE block in each 128B line -> every flag line has
// exactly one writer block. Poller reads 128 slots with 2 lane-strided agent
// loads (64 parallel MALL requests, one RT).
__global__ __launch_bounds__(512, 2) void gru_persistent(
        const unsigned short* __restrict__ gi,   // [256][64][3072] bf16 (incl b_ih)
        const unsigned short* __restrict__ whh,  // [3072][1024] bf16
        const float* __restrict__ b_hh,          // [3072]
        unsigned short* __restrict__ hs,         // tiled: [256][2][64][2][16][16] bf16
        unsigned int* flags) {                   // padded: [256][2][128][FPAD]
    const int tid = threadIdx.x;
    const int lane = tid & 63, wv = tid >> 6;
    const int mt = wv & 1, kh = wv >> 1;         // kh 0..3
    const int q = lane >> 4, l15 = lane & 15;
    const int jc = blockIdx.x >> 1, mh = blockIdx.x & 1;
    const int j = jc * 16 + l15;                 // h-col 0..1023
    const int brow0 = mh * 32 + mt * 16;         // wave's 16 batch rows

    __shared__ float red[2][3][2][3][64][4];     // [s&1][kh-1][mt][g][lane][r] = 36 KB

    // ---- register-resident weight fragments: rows {j, 1024+j, 2048+j}, K quarter kh ----
    short8 wfrag[3][8];
#pragma unroll
    for (int g = 0; g < 3; g++)
#pragma unroll
        for (int kk = 0; kk < 8; kk++)
            wfrag[g][kk] = ld8(whh + (size_t)(g * 1024 + j) * DH + kh * 256 + kk * 32 + q * 8);

    float bhr = 0.f, bhz = 0.f, bhn = 0.f;
    float hreg[4];
    float gir[4], giz[4], gin[4];
    if (kh == 0) {
        bhr = b_hh[j]; bhz = b_hh[1024 + j]; bhn = b_hh[2048 + j];
#pragma unroll
        for (int r = 0; r < 4; r++) {
            hreg[r] = 0.f;
            int b = brow0 + q * 4 + r;           // initial gi prefetch (s=0)
            gir[r] = bf2f(gi[(size_t)b * G3 + j]);
            giz[r] = bf2f(gi[(size_t)b * G3 + 1024 + j]);
            gin[r] = bf2f(gi[(size_t)b * G3 + 2048 + j]);
        }
    }

    for (int s = 0; s < S_; s++) {
        const int pb = s & 1;
        // ---- MFMA phase: gh partials for this K quarter ----
        floatx4 zf = {0.f, 0.f, 0.f, 0.f};
        floatx4 acc[3] = {zf, zf, zf};
        if (s > 0) {
            // tiled read: A rows = mh*32 + mt*16 + l15; k = kh*256 + kk*32 + q*8
            // -> source tile jc_k = kh*16 + kk*2 + (q>>1), 16B half (q&1).
            const unsigned short* hb =
                hs + ((size_t)((s - 1) * 2 + mh) * 64) * 512 + mt * 256
                   + l15 * 16 + (q & 1) * 8;
            const int jbase = (kh * 16 + (q >> 1)) * 512;
#pragma unroll
            for (int kk = 0; kk < 8; kk++) {
                short8 a = ld8(hb + jbase + kk * 1024);  // kk*2 tiles = 1024 ushort
#pragma unroll
                for (int g = 0; g < 3; g++)
                    acc[g] = MFMA(a, wfrag[g][kk], acc[g]);
            }
        }

        // ---- cross-wave K reduction (vector LDS writes) ----
        if (kh > 0) {
#pragma unroll
            for (int g = 0; g < 3; g++)
                *reinterpret_cast<floatx4*>(&red[pb][kh - 1][mt][g][lane][0]) = acc[g];
        }
        // red handoff: LDS writes visible, then raw barrier (no vmcnt drain -
        // outstanding gi prefetch / flag stores stay in flight).
        asm volatile("s_waitcnt lgkmcnt(0)" ::: "memory");
        __builtin_amdgcn_s_barrier();
        asm volatile("" ::: "memory");

        if (kh == 0) {
            // ---- gate phase (the two kh==0 waves) ----
#pragma unroll
            for (int p = 0; p < 3; p++)
#pragma unroll
                for (int g = 0; g < 3; g++) {
                    floatx4 v = *reinterpret_cast<const floatx4*>(&red[pb][p][mt][g][lane][0]);
                    acc[g] += v;
                }
            // this wave's OWN 512B tile: [s][mh][jc][mt][16][16]
            uint32_t* ht = (uint32_t*)(hs +
                ((size_t)(s * 2 + mh) * 64 + jc) * 512 + mt * 256);
#pragma unroll
            for (int r = 0; r < 4; r++) {
                float rg = fast_sigmoid(gir[r] + acc[0][r] + bhr);
                float zg = fast_sigmoid(giz[r] + acc[1][r] + bhz);
                float ng = fast_tanh(gin[r] + rg * (acc[2][r] + bhn));
                float h = (1.f - zg) * ng + zg * hreg[r];
                hreg[r] = h;
                // pack bf16 pair across adjacent lanes (tile cols l15, l15+1)
                float hnb = __shfl_xor(h, 1);
                if ((l15 & 1) == 0) {
                    uint32_t pk = (uint32_t)f2bf(h) | ((uint32_t)f2bf(hnb) << 16);
                    // tile row = q*4+r (stride 8 dwords), col pair l15>>1.
                    // 4 store instrs fully cover the 4-line tile: single-writer
                    // lines, no cross-XCD merge.
                    AGENT_ST_U32(&ht[(q * 4 + r) * 8 + (l15 >> 1)], pk);
                }
            }
            if (s + 1 < S_) {
                // own-wave drain: stores at coherence point once vmcnt==0.
                // Then publish this wave's flag (single-writer 64B slot).
                asm volatile("" ::: "memory");
                asm volatile("s_waitcnt vmcnt(0)" ::: "memory");
                if (lane == 0)
                    AGENT_ST_U32(&flags[(((s << 1) + mh) * 128 + jc * 2 + mt) * FPAD], 1u);
                // gi prefetch for s+1 AFTER publish: HBM latency off the chain
                const unsigned short* gp = gi + (size_t)(s + 1) * B_ * G3;
#pragma unroll
                for (int r = 0; r < 4; r++) {
                    int b = brow0 + q * 4 + r;
                    gir[r] = bf2f(gp[(size_t)b * G3 + j]);
                    giz[r] = bf2f(gp[(size_t)b * G3 + 1024 + j]);
                    gin[r] = bf2f(gp[(size_t)b * G3 + 2048 + j]);
                }
            }
        } else if (wv == 7) {
            // ---- dedicated poller wave: wait for all 128 producer flags of
            // step s (my mh half). 2 lane-strided loads over the padded slots.
            if (s + 1 < S_) {
                const unsigned int* fp =
                    flags + ((s << 1) + mh) * 128 * FPAD + lane * FPAD;
                for (;;) {
                    unsigned int f0 = AGENT_LD_U32(fp);
                    unsigned int f1 = AGENT_LD_U32(fp + 64 * FPAD);
                    if (__all((f0 != 0u) && (f1 != 0u))) break;
                    __builtin_amdgcn_s_sleep(1);
                }
                asm volatile("" ::: "memory");
            }
        }
        // waves 2..6 fall straight through and PARK here (no spin traffic).
        asm volatile("" ::: "memory");
        __builtin_amdgcn_s_barrier();
        asm volatile("" ::: "memory");
    }
}

// ---------------- FC + log_softmax, fused (tiled hs reader) ----------------
__global__ __launch_bounds__(256) void fc_logsoftmax(
        const unsigned short* __restrict__ hs,    // tiled: [256][2][64][2][16][16]
        const unsigned short* __restrict__ fcw,   // [64][1024] bf16
        const float* __restrict__ fcb,            // [64]
        float* __restrict__ out) {                // [B][S][64]
    int tid = threadIdx.x;
    int lane = tid & 63, mt = tid >> 6;
    int q = lane >> 4, l15 = lane & 15;
    int s = blockIdx.x;                          // rows s*64 .. s*64+63

    floatx4 acc[4];
    floatx4 z = {0.f, 0.f, 0.f, 0.f};
    for (int nt = 0; nt < 4; nt++) acc[nt] = z;

    // A row b = mt*16 + l15 -> half mh=b>>5, producer tile mtb=(b>>4)&1, row b&15
    int b = mt * 16 + l15;
    int mh = b >> 5, mtb = (b >> 4) & 1, r16 = b & 15;
    const unsigned short* Ab =
        hs + ((size_t)(s * 2 + mh) * 64) * 512 + mtb * 256
           + r16 * 16 + (q & 1) * 8;
    const int jq = (q >> 1) * 512;               // jc half-step from q
    const unsigned short* Wp = fcw + (size_t)l15 * DH + q * 8;
    for (int k0 = 0; k0 < DH; k0 += 32) {
        // k = k0 + q*8 (+0..7): source tile jc = (k0>>4) + (q>>1)
        short8 a = ld8(Ab + (k0 >> 4) * 512 + jq);
        for (int nt = 0; nt < 4; nt++)
            acc[nt] = MFMA(a, ld8(Wp + (size_t)nt * 16 * DH + k0), acc[nt]);
    }

    float bv[4];
    for (int nt = 0; nt < 4; nt++) bv[nt] = fcb[nt * 16 + l15];

    for (int r = 0; r < 4; r++) {
        float v[4];
        for (int nt = 0; nt < 4; nt++) v[nt] = acc[nt][r] + bv[nt];
        float m = fmaxf(fmaxf(v[0], v[1]), fmaxf(v[2], v[3]));
        for (int off = 1; off < 16; off <<= 1) m = fmaxf(m, __shfl_xor(m, off));
        float se = __expf(v[0] - m) + __expf(v[1] - m) + __expf(v[2] - m) + __expf(v[3] - m);
        for (int off = 1; off < 16; off <<= 1) se += __shfl_xor(se, off);
        float L = logf(se);
        int brow = mt * 16 + q * 4 + r;          // C-frag row = batch index
        float* op = out + (size_t)(brow * S_ + s) * DOUT;
        for (int nt = 0; nt < 4; nt++) op[nt * 16 + l15] = v[nt] - m - L;
    }
}

extern "C" void kernel_launch(void* const* d_in, const int* in_sizes, int n_in,
                              void* d_out, int out_size, void* d_ws, size_t ws_size,
                              hipStream_t stream) {
    const int*   x    = (const int*)d_in[0];
    const float* emb  = (const float*)d_in[1];
    const float* w_ih = (const float*)d_in[2];
    const float* w_hh = (const float*)d_in[3];
    const float* b_ih = (const float*)d_in[4];
    const float* b_hh = (const float*)d_in[5];
    const float* fc_w = (const float*)d_in[6];
    const float* fc_b = (const float*)d_in[7];
    float* out = (float*)d_out;

    char* p = (char*)d_ws;
    unsigned int*   flags = (unsigned int*)p;   p += (size_t)NFLAG * 4;      // 4 MB
    unsigned short* xe    = (unsigned short*)p; p += (size_t)M_ * DIN * 2;   // 16 MB
    unsigned short* gi    = (unsigned short*)p; p += (size_t)M_ * G3 * 2;    // 100.7 MB
    unsigned short* wih_b = (unsigned short*)p; p += (size_t)G3 * DIN * 2;   // 3 MB
    unsigned short* whh_b = (unsigned short*)p; p += (size_t)G3 * DH * 2;    // 6.3 MB
    unsigned short* fcw_b = (unsigned short*)p; p += (size_t)DOUT * DH * 2;  // 128 KB
    unsigned short* hs    = (unsigned short*)p; p += (size_t)M_ * DH * 2;    // 33.6 MB

    init_flags_kernel<<<(NFLAG + 255) / 256, 256, 0, stream>>>(flags);
    cast_bf16_kernel<<<(G3 * DIN + 255) / 256, 256, 0, stream>>>(w_ih, wih_b, G3 * DIN);
    cast_bf16_kernel<<<(G3 * DH + 255) / 256, 256, 0, stream>>>(w_hh, whh_b, G3 * DH);
    cast_bf16_kernel<<<(DOUT * DH + 255) / 256, 256, 0, stream>>>(fc_w, fcw_b, DOUT * DH);
    gather_kernel<<<(M_ * DIN) / 256, 256, 0, stream>>>(x, emb, xe);

    gemm_bt_bias<<<dim3(M_ / 128, G3 / 128), 256, 0, stream>>>(
        xe, wih_b, b_ih, gi, M_, G3, DIN);

    gru_persistent<<<NBLK, 512, 0, stream>>>(gi, whh_b, b_hh, hs, flags);

    fc_logsoftmax<<<S_, 256, 0, stream>>>(hs, fcw_b, fc_b, out);
}

// Round 11
// 1168.663 us; speedup vs baseline: 3.8825x; 1.0027x over previous
//
#include <hip/hip_runtime.h>
#include <stdint.h>
#include <math.h>

typedef short short8 __attribute__((ext_vector_type(8)));
typedef float floatx4 __attribute__((ext_vector_type(4)));

#define MFMA(a, b, c) __builtin_amdgcn_mfma_f32_16x16x32_bf16((a), (b), (c), 0, 0, 0)

#define B_   64
#define S_   256
#define DIN  512
#define DH   1024
#define G3   3072
#define DOUT 64
#define M_   (B_ * S_)  // 16384
#define NBLK 128        // persistent blocks: 64 col-chunks x 2 batch halves
#define FPAD 16         // dwords per flag slot (64B): 128B line = 2 slots = ONE block
#define NFLAG (S_ * 2 * 128 * FPAD)  // padded [s][mh][jc*2+mt] ready flags (4MB)

#define AGENT_LD_U32(p) __hip_atomic_load((p), __ATOMIC_RELAXED, __HIP_MEMORY_SCOPE_AGENT)
#define AGENT_ST_U32(p, v) __hip_atomic_store((p), (v), __ATOMIC_RELAXED, __HIP_MEMORY_SCOPE_AGENT)

__device__ __forceinline__ unsigned short f2bf(float f) {
    union { float f; uint32_t u; } v; v.f = f;
    uint32_t u = v.u;
    uint32_t r = (u + 0x7fffu + ((u >> 16) & 1u)) >> 16;  // RNE
    return (unsigned short)r;
}
__device__ __forceinline__ float bf2f(unsigned short s) {
    union { uint32_t u; float f; } v; v.u = ((uint32_t)s) << 16; return v.f;
}
__device__ __forceinline__ short8 ld8(const unsigned short* p) {
    return *reinterpret_cast<const short8*>(p);
}
__device__ __forceinline__ float fast_sigmoid(float x) {
    return 1.f / (1.f + __expf(-x));
}
__device__ __forceinline__ float fast_tanh(float x) {
    return 1.f - 2.f / (__expf(2.f * x) + 1.f);
}

// ---------------- elementwise: fp32 -> bf16 cast ----------------
__global__ void cast_bf16_kernel(const float* __restrict__ src,
                                 unsigned short* __restrict__ dst, int n) {
    int i = blockIdx.x * 256 + threadIdx.x;
    if (i < n) dst[i] = f2bf(src[i]);
}

// ---------------- zero the flag region (ws is poisoned 0xAA!) ----------------
__global__ void init_flags_kernel(unsigned int* flags) {
    int i = blockIdx.x * 256 + threadIdx.x;
    if (i < NFLAG) flags[i] = 0u;
}

// ---------------- embedding gather into [s*64+b][512] bf16 ----------------
__global__ void gather_kernel(const int* __restrict__ x, const float* __restrict__ emb,
                              unsigned short* __restrict__ xe) {
    int g = blockIdx.x * 256 + threadIdx.x;  // 16384*512 total
    int m = g >> 9;          // row = s*64+b
    int k = g & 511;
    int s = m >> 6, b = m & 63;
    int tok = x[b * S_ + s];
    xe[(size_t)m * DIN + k] = f2bf(emb[(size_t)tok * DIN + k]);
}

// ---------------- bt-GEMM: C[M,N] bf16 = A[M,K] @ W[N,K]^T + bias ----------------
__global__ __launch_bounds__(256) void gemm_bt_bias(
        const unsigned short* __restrict__ A, const unsigned short* __restrict__ W,
        const float* __restrict__ bias, unsigned short* __restrict__ C,
        int M, int N, int K) {
    __shared__ __align__(16) unsigned short As[128 * 32];
    __shared__ __align__(16) unsigned short Ws[128 * 32];
    int tid = threadIdx.x;
    int lane = tid & 63, wv = tid >> 6;
    int wm = wv >> 1, wn = wv & 1;
    int q = lane >> 4, l15 = lane & 15;
    int bm = blockIdx.x, bn = blockIdx.y;

    floatx4 acc[4][4];
    floatx4 z = {0.f, 0.f, 0.f, 0.f};
    for (int i = 0; i < 4; i++) for (int j = 0; j < 4; j++) acc[i][j] = z;

    int row_s = tid >> 1;
    int col_s = (tid & 1) * 16;
    const unsigned short* Ab = A + (size_t)(bm * 128 + row_s) * K + col_s;
    const unsigned short* Wb = W + (size_t)(bn * 128 + row_s) * K + col_s;
    unsigned short* AsW = &As[row_s * 32 + col_s];
    unsigned short* WsW = &Ws[row_s * 32 + col_s];

    for (int k0 = 0; k0 < K; k0 += 32) {
        __syncthreads();
        *reinterpret_cast<short8*>(AsW)     = ld8(Ab + k0);
        *reinterpret_cast<short8*>(AsW + 8) = ld8(Ab + k0 + 8);
        *reinterpret_cast<short8*>(WsW)     = ld8(Wb + k0);
        *reinterpret_cast<short8*>(WsW + 8) = ld8(Wb + k0 + 8);
        __syncthreads();
        short8 af[4], wf[4];
        for (int t = 0; t < 4; t++) {
            af[t] = ld8(&As[(wm * 64 + t * 16 + l15) * 32 + q * 8]);
            wf[t] = ld8(&Ws[(wn * 64 + t * 16 + l15) * 32 + q * 8]);
        }
        for (int i = 0; i < 4; i++)
            for (int j = 0; j < 4; j++)
                acc[i][j] = MFMA(af[i], wf[j], acc[i][j]);
    }
    for (int i = 0; i < 4; i++) {
        int row = bm * 128 + wm * 64 + i * 16 + q * 4;
        for (int j = 0; j < 4; j++) {
            int col = bn * 128 + wn * 64 + j * 16 + l15;
            float bv = bias[col];
            for (int r = 0; r < 4; r++)
                C[(size_t)(row + r) * N + col] = f2bf(acc[i][j][r] + bv);
        }
    }
}

// ---------------- persistent GRU recurrence ----------------
// R10 skeleton (947us): tiled single-writer hs (R9, -150us), padded
// single-writer flag slots (R10, -440us), raw barriers, vmcnt(0) drain before
// publish, gi prefetch after.
//
// ONE change this round: kill the 128-wide fan-in. Wave (mt,kh) consumes only
// the 16 tiles jc' = kh*16..kh*16+15 of its own mt/mh -- 16 producer blocks,
// not 128. The central poller (max over 128 completion times) + the release
// barrier re-coupled everything. Now EACH wave polls its own 16 flags (lane
// l15 -> producer jc' = kh*16+l15) at the top of the step, then loads h.
// Poller wave and barrier #2 are gone; one barrier per step remains for the
// red[] handoff.
//   red[] double-buffer safety with ONE barrier: reads of red[pb] at step s
//   happen between barrier(s) and barrier(s+1); the next write of red[pb]
//   (step s+2) happens after barrier(s+1). Separated -> safe.
//   Liveness: flags(s) published unconditionally by kh=0 waves after
//   barrier(s); consumers at s+1 wait only on flags(s) -> no circular wait;
//   all 8 waves execute the single barrier unconditionally.
// Effect: fan-in max-of-128 -> max-of-16, one barrier convergence removed,
// blocks self-skew (early producers unblock their consumers early).
__global__ __launch_bounds__(512, 2) void gru_persistent(
        const unsigned short* __restrict__ gi,   // [256][64][3072] bf16 (incl b_ih)
        const unsigned short* __restrict__ whh,  // [3072][1024] bf16
        const float* __restrict__ b_hh,          // [3072]
        unsigned short* __restrict__ hs,         // tiled: [256][2][64][2][16][16] bf16
        unsigned int* flags) {                   // padded: [256][2][128][FPAD]
    const int tid = threadIdx.x;
    const int lane = tid & 63, wv = tid >> 6;
    const int mt = wv & 1, kh = wv >> 1;         // kh 0..3
    const int q = lane >> 4, l15 = lane & 15;
    const int jc = blockIdx.x >> 1, mh = blockIdx.x & 1;
    const int j = jc * 16 + l15;                 // h-col 0..1023
    const int brow0 = mh * 32 + mt * 16;         // wave's 16 batch rows

    __shared__ float red[2][3][2][3][64][4];     // [s&1][kh-1][mt][g][lane][r] = 36 KB

    // ---- register-resident weight fragments: rows {j, 1024+j, 2048+j}, K quarter kh ----
    short8 wfrag[3][8];
#pragma unroll
    for (int g = 0; g < 3; g++)
#pragma unroll
        for (int kk = 0; kk < 8; kk++)
            wfrag[g][kk] = ld8(whh + (size_t)(g * 1024 + j) * DH + kh * 256 + kk * 32 + q * 8);

    float bhr = 0.f, bhz = 0.f, bhn = 0.f;
    float hreg[4];
    float gir[4], giz[4], gin[4];
    if (kh == 0) {
        bhr = b_hh[j]; bhz = b_hh[1024 + j]; bhn = b_hh[2048 + j];
#pragma unroll
        for (int r = 0; r < 4; r++) {
            hreg[r] = 0.f;
            int b = brow0 + q * 4 + r;           // initial gi prefetch (s=0)
            gir[r] = bf2f(gi[(size_t)b * G3 + j]);
            giz[r] = bf2f(gi[(size_t)b * G3 + 1024 + j]);
            gin[r] = bf2f(gi[(size_t)b * G3 + 2048 + j]);
        }
    }

    // my 16 producer flag slots for K quarter kh: jc' = kh*16 + l15, own mt/mh.
    // 4 lanes share each address (broadcast) -> 16 distinct 64B slots, one RT.
    const unsigned int* fbase =
        flags + ((kh * 16 + l15) * 2 + mt) * FPAD + mh * 128 * FPAD;

    for (int s = 0; s < S_; s++) {
        const int pb = s & 1;
        // ---- wait for MY 16 producers of step s-1, then MFMA phase ----
        floatx4 zf = {0.f, 0.f, 0.f, 0.f};
        floatx4 acc[3] = {zf, zf, zf};
        if (s > 0) {
            const unsigned int* fp = fbase + (size_t)((s - 1) << 1) * 128 * FPAD;
            while (!__all(AGENT_LD_U32(fp) != 0u)) {
                __builtin_amdgcn_s_sleep(1);
            }
            asm volatile("" ::: "memory");

            // tiled read: A rows = mh*32 + mt*16 + l15; k = kh*256 + kk*32 + q*8
            // -> source tile jc_k = kh*16 + kk*2 + (q>>1), 16B half (q&1).
            const unsigned short* hb =
                hs + ((size_t)((s - 1) * 2 + mh) * 64) * 512 + mt * 256
                   + l15 * 16 + (q & 1) * 8;
            const int jbase = (kh * 16 + (q >> 1)) * 512;
#pragma unroll
            for (int kk = 0; kk < 8; kk++) {
                short8 a = ld8(hb + jbase + kk * 1024);  // kk*2 tiles = 1024 ushort
#pragma unroll
                for (int g = 0; g < 3; g++)
                    acc[g] = MFMA(a, wfrag[g][kk], acc[g]);
            }
        }

        // ---- cross-wave K reduction (vector LDS writes) ----
        if (kh > 0) {
#pragma unroll
            for (int g = 0; g < 3; g++)
                *reinterpret_cast<floatx4*>(&red[pb][kh - 1][mt][g][lane][0]) = acc[g];
        }
        // red handoff: LDS writes visible, then the ONE barrier per step.
        asm volatile("s_waitcnt lgkmcnt(0)" ::: "memory");
        __builtin_amdgcn_s_barrier();
        asm volatile("" ::: "memory");

        if (kh == 0) {
            // ---- gate phase (the two kh==0 waves) ----
#pragma unroll
            for (int p = 0; p < 3; p++)
#pragma unroll
                for (int g = 0; g < 3; g++) {
                    floatx4 v = *reinterpret_cast<const floatx4*>(&red[pb][p][mt][g][lane][0]);
                    acc[g] += v;
                }
            // this wave's OWN 512B tile: [s][mh][jc][mt][16][16]
            uint32_t* ht = (uint32_t*)(hs +
                ((size_t)(s * 2 + mh) * 64 + jc) * 512 + mt * 256);
#pragma unroll
            for (int r = 0; r < 4; r++) {
                float rg = fast_sigmoid(gir[r] + acc[0][r] + bhr);
                float zg = fast_sigmoid(giz[r] + acc[1][r] + bhz);
                float ng = fast_tanh(gin[r] + rg * (acc[2][r] + bhn));
                float h = (1.f - zg) * ng + zg * hreg[r];
                hreg[r] = h;
                // pack bf16 pair across adjacent lanes (tile cols l15, l15+1)
                float hnb = __shfl_xor(h, 1);
                if ((l15 & 1) == 0) {
                    uint32_t pk = (uint32_t)f2bf(h) | ((uint32_t)f2bf(hnb) << 16);
                    // tile row = q*4+r (stride 8 dwords), col pair l15>>1.
                    // 4 store instrs fully cover the 4-line tile: single-writer
                    // lines, no cross-XCD merge.
                    AGENT_ST_U32(&ht[(q * 4 + r) * 8 + (l15 >> 1)], pk);
                }
            }
            if (s + 1 < S_) {
                // own-wave drain: stores at coherence point once vmcnt==0.
                // Then publish this wave's flag (single-writer 64B slot).
                asm volatile("" ::: "memory");
                asm volatile("s_waitcnt vmcnt(0)" ::: "memory");
                if (lane == 0)
                    AGENT_ST_U32(&flags[(((s << 1) + mh) * 128 + jc * 2 + mt) * FPAD], 1u);
                // gi prefetch for s+1 AFTER publish: HBM latency off the chain
                const unsigned short* gp = gi + (size_t)(s + 1) * B_ * G3;
#pragma unroll
                for (int r = 0; r < 4; r++) {
                    int b = brow0 + q * 4 + r;
                    gir[r] = bf2f(gp[(size_t)b * G3 + j]);
                    giz[r] = bf2f(gp[(size_t)b * G3 + 1024 + j]);
                    gin[r] = bf2f(gp[(size_t)b * G3 + 2048 + j]);
                }
            }
        }
        // kh>0 waves fall straight into step s+1: they self-time on their own
        // 16 producer flags (no release barrier needed).
    }
}

// ---------------- FC + log_softmax, fused (tiled hs reader) ----------------
__global__ __launch_bounds__(256) void fc_logsoftmax(
        const unsigned short* __restrict__ hs,    // tiled: [256][2][64][2][16][16]
        const unsigned short* __restrict__ fcw,   // [64][1024] bf16
        const float* __restrict__ fcb,            // [64]
        float* __restrict__ out) {                // [B][S][64]
    int tid = threadIdx.x;
    int lane = tid & 63, mt = tid >> 6;
    int q = lane >> 4, l15 = lane & 15;
    int s = blockIdx.x;                          // rows s*64 .. s*64+63

    floatx4 acc[4];
    floatx4 z = {0.f, 0.f, 0.f, 0.f};
    for (int nt = 0; nt < 4; nt++) acc[nt] = z;

    // A row b = mt*16 + l15 -> half mh=b>>5, producer tile mtb=(b>>4)&1, row b&15
    int b = mt * 16 + l15;
    int mh = b >> 5, mtb = (b >> 4) & 1, r16 = b & 15;
    const unsigned short* Ab =
        hs + ((size_t)(s * 2 + mh) * 64) * 512 + mtb * 256
           + r16 * 16 + (q & 1) * 8;
    const int jq = (q >> 1) * 512;               // jc half-step from q
    const unsigned short* Wp = fcw + (size_t)l15 * DH + q * 8;
    for (int k0 = 0; k0 < DH; k0 += 32) {
        // k = k0 + q*8 (+0..7): source tile jc = (k0>>4) + (q>>1)
        short8 a = ld8(Ab + (k0 >> 4) * 512 + jq);
        for (int nt = 0; nt < 4; nt++)
            acc[nt] = MFMA(a, ld8(Wp + (size_t)nt * 16 * DH + k0), acc[nt]);
    }

    float bv[4];
    for (int nt = 0; nt < 4; nt++) bv[nt] = fcb[nt * 16 + l15];

    for (int r = 0; r < 4; r++) {
        float v[4];
        for (int nt = 0; nt < 4; nt++) v[nt] = acc[nt][r] + bv[nt];
        float m = fmaxf(fmaxf(v[0], v[1]), fmaxf(v[2], v[3]));
        for (int off = 1; off < 16; off <<= 1) m = fmaxf(m, __shfl_xor(m, off));
        float se = __expf(v[0] - m) + __expf(v[1] - m) + __expf(v[2] - m) + __expf(v[3] - m);
        for (int off = 1; off < 16; off <<= 1) se += __shfl_xor(se, off);
        float L = logf(se);
        int brow = mt * 16 + q * 4 + r;          // C-frag row = batch index
        float* op = out + (size_t)(brow * S_ + s) * DOUT;
        for (int nt = 0; nt < 4; nt++) op[nt * 16 + l15] = v[nt] - m - L;
    }
}

extern "C" void kernel_launch(void* const* d_in, const int* in_sizes, int n_in,
                              void* d_out, int out_size, void* d_ws, size_t ws_size,
                              hipStream_t stream) {
    const int*   x    = (const int*)d_in[0];
    const float* emb  = (const float*)d_in[1];
    const float* w_ih = (const float*)d_in[2];
    const float* w_hh = (const float*)d_in[3];
    const float* b_ih = (const float*)d_in[4];
    const float* b_hh = (const float*)d_in[5];
    const float* fc_w = (const float*)d_in[6];
    const float* fc_b = (const float*)d_in[7];
    float* out = (float*)d_out;

    char* p = (char*)d_ws;
    unsigned int*   flags = (unsigned int*)p;   p += (size_t)NFLAG * 4;      // 4 MB
    unsigned short* xe    = (unsigned short*)p; p += (size_t)M_ * DIN * 2;   // 16 MB
    unsigned short* gi    = (unsigned short*)p; p += (size_t)M_ * G3 * 2;    // 100.7 MB
    unsigned short* wih_b = (unsigned short*)p; p += (size_t)G3 * DIN * 2;   // 3 MB
    unsigned short* whh_b = (unsigned short*)p; p += (size_t)G3 * DH * 2;    // 6.3 MB
    unsigned short* fcw_b = (unsigned short*)p; p += (size_t)DOUT * DH * 2;  // 128 KB
    unsigned short* hs    = (unsigned short*)p; p += (size_t)M_ * DH * 2;    // 33.6 MB

    init_flags_kernel<<<(NFLAG + 255) / 256, 256, 0, stream>>>(flags);
    cast_bf16_kernel<<<(G3 * DIN + 255) / 256, 256, 0, stream>>>(w_ih, wih_b, G3 * DIN);
    cast_bf16_kernel<<<(G3 * DH + 255) / 256, 256, 0, stream>>>(w_hh, whh_b, G3 * DH);
    cast_bf16_kernel<<<(DOUT * DH + 255) / 256, 256, 0, stream>>>(fc_w, fcw_b, DOUT * DH);
    gather_kernel<<<(M_ * DIN) / 256, 256, 0, stream>>>(x, emb, xe);

    gemm_bt_bias<<<dim3(M_ / 128, G3 / 128), 256, 0, stream>>>(
        xe, wih_b, b_ih, gi, M_, G3, DIN);

    gru_persistent<<<NBLK, 512, 0, stream>>>(gi, whh_b, b_hh, hs, flags);

    fc_logsoftmax<<<S_, 256, 0, stream>>>(hs, fcw_b, fc_b, out);
}